// Round 1
// 730.415 us; speedup vs baseline: 1.1356x; 1.1356x over previous
//
#include <hip/hip_runtime.h>
#include <cstdint>
#include <cstddef>

#define NROWS 4096   // B*N
#define VDIM  32000
#define NDIM  2048   // N
#define KDIM  1024   // D
#define CDIM  512    // D/2
#define KTAPS 16     // alpha^16 ~ 1.1e-7: full fp32 accuracy for the IIR

#define GEMM_BLOCKS 512          // (NROWS/64) * (CDIM/64)
#define FUSED_GRID  (GEMM_BLOCKS + NROWS)

// ---------------- threefry2x32 (matches JAX/Random123, 20 rounds) ----------------
__device__ __forceinline__ uint32_t rotl32(uint32_t v, int r){ return (v<<r)|(v>>(32-r)); }

__device__ __forceinline__ void threefry2x32(uint32_t k0, uint32_t k1, uint32_t c0, uint32_t c1,
                                             uint32_t& o0, uint32_t& o1){
  uint32_t ks2 = k0 ^ k1 ^ 0x1BD11BDAu;
  uint32_t x0 = c0 + k0, x1 = c1 + k1;
  x0+=x1; x1=rotl32(x1,13); x1^=x0;
  x0+=x1; x1=rotl32(x1,15); x1^=x0;
  x0+=x1; x1=rotl32(x1,26); x1^=x0;
  x0+=x1; x1=rotl32(x1, 6); x1^=x0;
  x0+=k1; x1+=ks2+1u;
  x0+=x1; x1=rotl32(x1,17); x1^=x0;
  x0+=x1; x1=rotl32(x1,29); x1^=x0;
  x0+=x1; x1=rotl32(x1,16); x1^=x0;
  x0+=x1; x1=rotl32(x1,24); x1^=x0;
  x0+=ks2; x1+=k0+2u;
  x0+=x1; x1=rotl32(x1,13); x1^=x0;
  x0+=x1; x1=rotl32(x1,15); x1^=x0;
  x0+=x1; x1=rotl32(x1,26); x1^=x0;
  x0+=x1; x1=rotl32(x1, 6); x1^=x0;
  x0+=k0; x1+=k1+3u;
  x0+=x1; x1=rotl32(x1,17); x1^=x0;
  x0+=x1; x1=rotl32(x1,29); x1^=x0;
  x0+=x1; x1=rotl32(x1,16); x1^=x0;
  x0+=x1; x1=rotl32(x1,24); x1^=x0;
  x0+=k1; x1+=ks2+4u;
  x0+=x1; x1=rotl32(x1,13); x1^=x0;
  x0+=x1; x1=rotl32(x1,15); x1^=x0;
  x0+=x1; x1=rotl32(x1,26); x1^=x0;
  x0+=x1; x1=rotl32(x1, 6); x1^=x0;
  x0+=ks2; x1+=k0+5u;
  o0=x0; o1=x1;
}

// XLA ErfInv32 (Giles polynomial) — what lax.erf_inv lowers to for f32
__device__ __forceinline__ float erfinvf_xla(float x){
  float w = -log1pf(-x*x);
  float p;
  if (w < 5.0f){
    w -= 2.5f;
    p =  2.81022636e-08f;
    p = fmaf(p,w, 3.43273939e-07f);
    p = fmaf(p,w,-3.5233877e-06f);
    p = fmaf(p,w,-4.39150654e-06f);
    p = fmaf(p,w, 0.00021858087f);
    p = fmaf(p,w,-0.00125372503f);
    p = fmaf(p,w,-0.00417768164f);
    p = fmaf(p,w, 0.246640727f);
    p = fmaf(p,w, 1.50140941f);
  } else {
    w = sqrtf(w) - 3.0f;
    p = -0.000200214257f;
    p = fmaf(p,w, 0.000100950558f);
    p = fmaf(p,w, 0.00134934322f);
    p = fmaf(p,w,-0.00367342844f);
    p = fmaf(p,w, 0.00573950773f);
    p = fmaf(p,w,-0.0076224613f);
    p = fmaf(p,w, 0.00943887047f);
    p = fmaf(p,w, 1.00167406f);
    p = fmaf(p,w, 2.83297682f);
  }
  return p*x;
}

// bits -> uniform in [nextafter(-1,0), 1) exactly as jax._uniform does for f32
__device__ __forceinline__ float bits_to_uniform(uint32_t bits){
  float u = __uint_as_float((bits >> 9) | 0x3f800000u) - 1.0f;  // [0,1)
  float v = fmaf(u, 2.0f, -0.99999994f);
  return fmaxf(-0.99999994f, v);
}

// ---------------- Fused K1+K2: one dispatch, two block roles ----------------
// blocks [0, 512):    tiled SGEMM (4096x1024 @ 1024x512) + tanh + dot(W2) partials
//                     (LDS/VALU-bound)
// blocks [512, 4608): softmax target prob -> error magnitude (HBM-bound)
// GEMM blocks are placed first in the grid so both roles are co-resident from
// dispatch start; the memory-bound softmax stream hides the GEMM's LDS/compute.
__global__ __launch_bounds__(256) void fused_sm_gemm(const float* __restrict__ pred,
                                                     const int* __restrict__ target,
                                                     const float* __restrict__ A,
                                                     const float* __restrict__ B,
                                                     const float* __restrict__ b1,
                                                     const float* __restrict__ W2,
                                                     float* __restrict__ err,
                                                     float* __restrict__ part){
  __shared__ float smem[3072];            // 12 KB: As(1024) + Bs(1024) + red(1024)
  const int tid = threadIdx.x;

  if (blockIdx.x < GEMM_BLOCKS){
    // ------------------ GEMM role ------------------
    const int mb = blockIdx.x >> 3;       // 64 row-blocks of 64
    const int nb = blockIdx.x & 7;        // 8 col-blocks of 64
    float (*As)[64] = reinterpret_cast<float(*)[64]>(smem);
    float (*Bs)[64] = reinterpret_cast<float(*)[64]>(smem + 1024);
    const int tx = tid & 15, ty = tid >> 4;
    float acc[4][4] = {{0.f}};

    for (int k0 = 0; k0 < KDIM; k0 += 16){
      {
        int m  = tid >> 2, kq = tid & 3;
        float4 a = *(const float4*)(A + (size_t)(mb*64 + m)*KDIM + k0 + kq*4);
        As[kq*4+0][m] = a.x; As[kq*4+1][m] = a.y; As[kq*4+2][m] = a.z; As[kq*4+3][m] = a.w;
        int kk = tid >> 4, n4 = tid & 15;
        float4 bv = *(const float4*)(B + (size_t)(k0 + kk)*CDIM + nb*64 + n4*4);
        *(float4*)&Bs[kk][n4*4] = bv;
      }
      __syncthreads();
      #pragma unroll
      for (int k = 0; k < 16; k++){
        float4 av = *(float4*)&As[k][ty*4];
        float4 bv = *(float4*)&Bs[k][tx*4];
        float aa[4] = {av.x, av.y, av.z, av.w};
        float bb[4] = {bv.x, bv.y, bv.z, bv.w};
        #pragma unroll
        for (int i = 0; i < 4; i++)
          #pragma unroll
          for (int j = 0; j < 4; j++)
            acc[i][j] = fmaf(aa[i], bb[j], acc[i][j]);
      }
      __syncthreads();
    }

    float (*red)[16] = reinterpret_cast<float(*)[16]>(smem + 2048);
    #pragma unroll
    for (int i = 0; i < 4; i++){
      float s = 0.f;
      #pragma unroll
      for (int j = 0; j < 4; j++){
        int n = nb*64 + tx*4 + j;
        float h = tanhf(acc[i][j] + b1[n]);
        s = fmaf(h, W2[n], s);
      }
      red[ty*4+i][tx] = s;
    }
    __syncthreads();
    if (tid < 64){
      float s = 0.f;
      #pragma unroll
      for (int t = 0; t < 16; t++) s += red[tid][t];
      part[(size_t)(mb*64 + tid)*8 + nb] = s;
    }
  } else {
    // ------------------ softmax role ------------------
    const int r = blockIdx.x - GEMM_BLOCKS;
    const float* row = pred + (size_t)r * VDIM;
    const float L2E = 1.44269504f;        // log2(e): do exp in base 2 (native v_exp_f32)
    float m = -3.4e38f, s = 0.0f;
    for (int i = tid*4; i < VDIM; i += 1024){
      float4 x = *(const float4*)(row + i);
      float mx = fmaxf(fmaxf(x.x, x.y), fmaxf(x.z, x.w));
      if (mx > m){ s *= exp2f((m - mx)*L2E); m = mx; }
      s += exp2f((x.x - m)*L2E) + exp2f((x.y - m)*L2E)
         + exp2f((x.z - m)*L2E) + exp2f((x.w - m)*L2E);
    }
    // wave reduce (64 lanes)
    #pragma unroll
    for (int o = 32; o > 0; o >>= 1){
      float m2 = __shfl_xor(m, o);
      float s2 = __shfl_xor(s, o);
      float M = fmaxf(m, m2);
      s = s*exp2f((m - M)*L2E) + s2*exp2f((m2 - M)*L2E);
      m = M;
    }
    float* lm = smem;
    float* ls = smem + 8;
    if ((tid & 63) == 0){ lm[tid>>6] = m; ls[tid>>6] = s; }
    __syncthreads();
    if (tid == 0){
      float M = lm[0], S = ls[0];
      #pragma unroll
      for (int w = 1; w < 4; w++){
        float M2 = fmaxf(M, lm[w]);
        S = S*exp2f((M - M2)*L2E) + ls[w]*exp2f((lm[w] - M2)*L2E);
        M = M2;
      }
      float t = row[target[r]];
      err[r] = 1.0f - exp2f((t - M)*L2E) / S;
    }
  }
}

// ---------------- K3: power iteration (one block per batch row) ----------------
__device__ __forceinline__ float blockReduce1024(float v, float* red){
  #pragma unroll
  for (int o = 32; o > 0; o >>= 1) v += __shfl_down(v, o);
  __syncthreads();                       // protect red reuse across calls
  if ((threadIdx.x & 63) == 0) red[threadIdx.x >> 6] = v;
  __syncthreads();
  float s = 0.f;
  #pragma unroll
  for (int i = 0; i < 16; i++) s += red[i];
  return s;
}

// Changes vs previous version:
//  * all 1024 threads active in the conv: tids [0,512) do the REAL-channel conv
//    (which produces w_i), tids [512,1024) do the IMAG-channel conv (produces
//    w_r). Disjoint output arrays -> no cross-thread communication.
//  * deferred normalization: b stays unnormalized in sbr/sbi; 1/||w|| is folded
//    into the next iteration's v = D*b*scale fill. Removes the per-iteration
//    2048-element scale pass + one __syncthreads. Final eigenvalue dot is
//    scaled once at the end (scale is uniform across threads).
__global__ __launch_bounds__(1024) void power_iter_kernel(const float* __restrict__ part,
                                                          const float* __restrict__ err,
                                                          const float* __restrict__ b2,
                                                          float* __restrict__ out,
                                                          int out_size){
  const int b = blockIdx.x;
  const int tid = threadIdx.x;
  __shared__ __align__(16) float sDv[NDIM];
  __shared__ __align__(16) float sbr[NDIM], sbi[NDIM];
  __shared__ __align__(16) float svr[NDIM + 2*KTAPS], svi[NDIM + 2*KTAPS];
  __shared__ float red[16];

  // alpha^k coefficients (alpha = f32(exp(-1)))
  float coef[KTAPS+1];
  {
    double a = (double)0.36787944117144233f;
    double p = 1.0;
    #pragma unroll
    for (int k = 0; k <= KTAPS; k++){ coef[k] = (float)p; p *= a; }
  }

  // JAX PRNG, partitionable path:
  uint32_t kr0, kr1, ki0, ki1;
  threefry2x32(0u, 42u, 0u, 0u, kr0, kr1);   // kr = keys[0]
  threefry2x32(0u, 42u, 0u, 1u, ki0, ki1);   // ki = keys[1]

  const float b2v = b2[0];
  float nrm_local = 0.f;
  // D = sqrt(err*softplus + 1e-9);  b0 = normal(kr) + i*normal(ki) (unnormalized)
  for (int n = tid; n < NDIM; n += 1024){
    int i = b*NDIM + n;
    float s = 0.f;
    #pragma unroll
    for (int j = 0; j < 8; j++) s += part[(size_t)i*8 + j];
    s += b2v;
    float sp = fmaxf(s, 0.f) + log1pf(expf(-fabsf(s)));   // softplus
    sDv[n] = sqrtf(err[i]*sp + 1e-9f);

    uint32_t r0, r1, q0, q1;
    threefry2x32(kr0, kr1, 0u, (uint32_t)i, r0, r1);
    threefry2x32(ki0, ki1, 0u, (uint32_t)i, q0, q1);
    uint32_t rb = r0 ^ r1;
    uint32_t ib = q0 ^ q1;
    float br = 1.41421356f * erfinvf_xla(bits_to_uniform(rb));
    float bi = 1.41421356f * erfinvf_xla(bits_to_uniform(ib));
    sbr[n] = br; sbi[n] = bi;
    nrm_local += br*br + bi*bi;
  }
  float scale;
  {
    float nrm = blockReduce1024(nrm_local, red);   // includes barrier after sbr/sbi writes
    scale = 1.0f / fmaxf(sqrtf(nrm), 1e-12f);
  }

  float er = 0.f, ei = 0.f;
  // 16 applications of w = D * (0.5j * conv_{alpha^|k|}) (D * b_normalized)
  for (int it = 0; it < 16; ++it){
    const bool fin = (it == 15);
    // stage v = D * (b * scale), zero-padded halo
    for (int idx = tid; idx < NDIM + 2*KTAPS; idx += 1024){
      int i = idx - KTAPS;
      bool in = (i >= 0) && (i < NDIM);
      float ds = in ? sDv[i] * scale : 0.f;
      svr[idx] = in ? ds * sbr[i] : 0.f;
      svi[idx] = in ? ds * sbi[i] : 0.f;
    }
    __syncthreads();

    float la = 0.f, lb = 0.f;
    {
      const int ch = tid >> 9;                 // 0: real conv, 1: imag conv
      const int t0 = (tid & 511) * 4;
      const float* __restrict__ src = ch ? svi : svr;
      float win[36];
      #pragma unroll
      for (int j = 0; j < 9; j++){
        float4 x = *(const float4*)&src[t0 + 4*j];
        win[4*j] = x.x; win[4*j+1] = x.y; win[4*j+2] = x.z; win[4*j+3] = x.w;
      }
      float s4[4];
      #pragma unroll
      for (int m = 0; m < 4; m++){
        float s = win[m + KTAPS];
        #pragma unroll
        for (int k = 1; k <= KTAPS; k++) s = fmaf(coef[k], win[m+KTAPS-k] + win[m+KTAPS+k], s);
        s4[m] = s;
      }
      if (ch == 0){
        // real-channel conv R_r -> w_i = 0.5 * D * R_r
        #pragma unroll
        for (int m = 0; m < 4; m++){
          float d  = sDv[t0 + m];
          float wi = 0.5f * d * s4[m];
          if (!fin){ sbi[t0+m] = wi; la += wi*wi; }
          else     { la += sbi[t0+m]*wi;          // bi * wi   (Re part)
                     lb += sbr[t0+m]*wi; }        // br * wi   (Im part)
        }
      } else {
        // imag-channel conv R_i -> w_r = -0.5 * D * R_i
        #pragma unroll
        for (int m = 0; m < 4; m++){
          float d  = sDv[t0 + m];
          float wr = -0.5f * d * s4[m];
          if (!fin){ sbr[t0+m] = wr; la += wr*wr; }
          else     { la += sbr[t0+m]*wr;          // br * wr   (Re part)
                     lb -= sbi[t0+m]*wr; }        // -bi * wr  (Im part)
        }
      }
    }
    if (!fin){
      float nrm = blockReduce1024(la, red);        // also orders sbr/sbi writes vs next fill
      scale = 1.0f / fmaxf(sqrtf(nrm), 1e-12f);
    } else {
      float s_er = blockReduce1024(la, red);
      float s_ei = blockReduce1024(lb, red);
      er = s_er * scale;                           // undo deferred normalization of b
      ei = s_ei * scale;
    }
  }

  if (tid == 0){
    const float PI = 3.14159274f;
    float phase = atan2f(ei, er);
    float intf  = fabsf(ei);
    out[b]     = intf * cosf(phase);               // resonance
    out[2 + b] = intf * fabsf(phase - PI) / PI;    // dissonance
    if (out_size >= 8){
      out[4 + b] = er;
      out[6 + b] = ei;
    } else {
      out[4 + b] = er;
    }
  }
}

extern "C" void kernel_launch(void* const* d_in, const int* in_sizes, int n_in,
                              void* d_out, int out_size, void* d_ws, size_t ws_size,
                              hipStream_t stream){
  (void)in_sizes; (void)n_in; (void)ws_size;
  const float* pred   = (const float*)d_in[0];
  const int*   target = (const int*)  d_in[1];
  const float* hs     = (const float*)d_in[2];
  const float* W1     = (const float*)d_in[3];
  const float* b1     = (const float*)d_in[4];
  const float* W2     = (const float*)d_in[5];
  const float* b2     = (const float*)d_in[6];
  float* out  = (float*)d_out;
  float* err  = (float*)d_ws;          // 4096 floats
  float* part = err + NROWS;           // 4096*8 floats

  fused_sm_gemm<<<FUSED_GRID, 256, 0, stream>>>(pred, target, hs, W1, b1, W2, err, part);
  power_iter_kernel<<<2, 1024, 0, stream>>>(part, err, b2, out, out_size);
}